// Round 5
// baseline (103.961 us; speedup 1.0000x reference)
//
#include <hip/hip_runtime.h>

#define N_SAMPLES 128
#define EPS 1e-10f

typedef float f4 __attribute__((ext_vector_type(4)));

// Persistent waves, grid-stride over ray-pairs, 1-deep software pipeline.
// One 64-lane wave handles TWO rays per iteration: lanes 0-31 -> even ray,
// lanes 32-63 -> odd ray. Each lane owns 4 consecutive samples:
//   alpha: one float4 / lane (512 B contiguous per ray)
//   rgb:   3 float4 / lane (lane's 12 floats start at channel 0)
// weights[s] = alpha[s] * prod_{j<s}(1 - alpha[j] + EPS)
__global__ __launch_bounds__(256) void VolumeRenderer_14336600834233_kernel(
    const f4* __restrict__ alpha4,
    const f4* __restrict__ rgb4,
    float* __restrict__ out,
    int n_pairs)
{
    const int wavesPerBlock = blockDim.x >> 6;
    const int nWaves = gridDim.x * wavesPerBlock;
    const int lane = threadIdx.x & 63;
    const int g    = lane >> 5;     // which ray of the pair
    const int l    = lane & 31;     // lane within the 32-lane group

    int pair = blockIdx.x * wavesPerBlock + (threadIdx.x >> 6);
    if (pair >= n_pairs) return;

    // ---- prologue: load first iteration ----
    int ray = pair * 2 + g;
    f4 av = alpha4[(size_t)ray * 32 + l];
    size_t rb = (size_t)ray * 96 + (size_t)l * 3;
    f4 x0 = rgb4[rb + 0];
    f4 x1 = rgb4[rb + 1];
    f4 x2 = rgb4[rb + 2];

    while (true) {
        // ---- issue next iteration's loads before touching this one's data ----
        const int npair = pair + nWaves;
        const bool more = npair < n_pairs;     // wave-uniform (n_pairs % nWaves == 0 case: uniform anyway)
        f4 nav, nx0, nx1, nx2;
        if (more) {
            const int nray = npair * 2 + g;
            nav = alpha4[(size_t)nray * 32 + l];
            const size_t nrb = (size_t)nray * 96 + (size_t)l * 3;
            nx0 = rgb4[nrb + 0];
            nx1 = rgb4[nrb + 1];
            nx2 = rgb4[nrb + 2];
        }

        // ---- compute current iteration ----
        const float f0 = 1.0f - av.x + EPS;
        const float f1 = 1.0f - av.y + EPS;
        const float f2 = 1.0f - av.z + EPS;
        const float f3 = 1.0f - av.w + EPS;
        const float p  = (f0 * f1) * (f2 * f3);

        // inclusive product-scan within each 32-lane group (5 steps)
        float incl = p;
        #pragma unroll
        for (int off = 1; off < 32; off <<= 1) {
            float v = __shfl_up(incl, off, 64);
            incl = (l >= off) ? incl * v : incl;
        }
        float excl = __shfl_up(incl, 1, 64);
        if (l == 0) excl = 1.0f;

        const float w0 = av.x * excl;
        const float t1 = excl * f0;
        const float w1 = av.y * t1;
        const float t2 = t1 * f1;
        const float w2 = av.z * t2;
        const float w3 = av.w * (t2 * f2);

        // x0 = [r0,g0,b0,r1]  x1 = [g1,b1,r2,g2]  x2 = [b2,r3,g3,b3]
        float cr = fmaf(w0, x0.x, fmaf(w1, x0.w, fmaf(w2, x1.z, w3 * x2.y)));
        float cg = fmaf(w0, x0.y, fmaf(w1, x1.x, fmaf(w2, x1.w, w3 * x2.z)));
        float cb = fmaf(w0, x0.z, fmaf(w1, x1.y, fmaf(w2, x2.x, w3 * x2.w)));

        // sum-reduce within each 32-lane group (5 shfl_xor steps)
        #pragma unroll
        for (int off = 16; off; off >>= 1) {
            cr += __shfl_xor(cr, off, 64);
            cg += __shfl_xor(cg, off, 64);
            cb += __shfl_xor(cb, off, 64);
        }

        if (l == 0) {
            const int oray = pair * 2 + g;
            float* o = out + (size_t)oray * 3;
            o[0] = cr;
            o[1] = cg;
            o[2] = cb;
        }

        if (!more) break;
        pair = npair;
        av = nav; x0 = nx0; x1 = nx1; x2 = nx2;
    }
}

extern "C" void kernel_launch(void* const* d_in, const int* in_sizes, int n_in,
                              void* d_out, int out_size, void* d_ws, size_t ws_size,
                              hipStream_t stream) {
    const f4* alpha4 = (const f4*)d_in[0];
    const f4* rgb4   = (const f4*)d_in[1];
    float* out = (float*)d_out;

    const int n_rays  = in_sizes[0] / N_SAMPLES;   // 262144
    const int n_pairs = n_rays / 2;                // 131072

    const int block = 256;                         // 4 waves per block
    const int grid  = 2048;                        // 8 blocks/CU -> 32 waves/CU; 8192 waves x 16 iters

    VolumeRenderer_14336600834233_kernel<<<grid, block, 0, stream>>>(
        alpha4, rgb4, out, n_pairs);
}

// Round 6
// 94.259 us; speedup vs baseline: 1.1029x; 1.1029x over previous
//
#include <hip/hip_runtime.h>

#define N_SAMPLES 128
#define EPS 1e-10f

// One 64-lane wave per ray. Lane i owns samples 2i and 2i+1.
// weights[s] = alpha[s] * prod_{j<s}(1 - alpha[j] + EPS)   (shift-by-1 transmittance)
// Best measured structure (R0: 93.7 us, ~5.7 TB/s effective = 91% of float4-copy ceiling).
__global__ __launch_bounds__(256) void VolumeRenderer_14336600834233_kernel(
    const float* __restrict__ alpha,
    const float* __restrict__ rgbs,
    float* __restrict__ out,
    int n_rays)
{
    const int wavesPerBlock = blockDim.x >> 6;
    const int ray  = blockIdx.x * wavesPerBlock + (threadIdx.x >> 6);
    const int lane = threadIdx.x & 63;
    if (ray >= n_rays) return;

    // ---- load 2 alpha samples (coalesced float2: 512 B per wave) ----
    const float2* a2 = (const float2*)alpha;
    const float2 a = a2[(size_t)ray * (N_SAMPLES / 2) + lane];
    const float f0 = 1.0f - a.x + EPS;
    const float f1 = 1.0f - a.y + EPS;
    const float p  = f0 * f1;              // lane-local product of its 2 factors

    // ---- inclusive product-scan across 64 lanes (6 shfl_up steps) ----
    float incl = p;
    #pragma unroll
    for (int off = 1; off < 64; off <<= 1) {
        float v = __shfl_up(incl, off, 64);
        if (lane >= off) incl *= v;
    }
    // exclusive scan: product of all pairs in lanes < i
    float excl = __shfl_up(incl, 1, 64);
    if (lane == 0) excl = 1.0f;

    // transmittance (shifted) at sample 2i is excl; at 2i+1 it's excl*f0
    const float w0 = a.x * excl;
    const float w1 = a.y * excl * f0;

    // ---- load rgb for both samples: 3 x float2 per lane (1536 B contiguous per wave) ----
    const float2* rg = (const float2*)rgbs;
    const size_t base = (size_t)ray * (N_SAMPLES * 3 / 2) + 3 * lane;
    const float2 v0 = rg[base + 0];   // (r0, g0)
    const float2 v1 = rg[base + 1];   // (b0, r1)
    const float2 v2 = rg[base + 2];   // (g1, b1)

    float cr = fmaf(w0, v0.x, w1 * v1.y);
    float cg = fmaf(w0, v0.y, w1 * v2.x);
    float cb = fmaf(w0, v1.x, w1 * v2.y);

    // ---- wave sum-reduction (6 shfl_xor steps) ----
    #pragma unroll
    for (int off = 32; off; off >>= 1) {
        cr += __shfl_xor(cr, off, 64);
        cg += __shfl_xor(cg, off, 64);
        cb += __shfl_xor(cb, off, 64);
    }

    if (lane == 0) {
        float* o = out + (size_t)ray * 3;
        o[0] = cr;
        o[1] = cg;
        o[2] = cb;
    }
}

extern "C" void kernel_launch(void* const* d_in, const int* in_sizes, int n_in,
                              void* d_out, int out_size, void* d_ws, size_t ws_size,
                              hipStream_t stream) {
    const float* alpha = (const float*)d_in[0];
    const float* rgbs  = (const float*)d_in[1];
    float* out = (float*)d_out;

    const int n_rays = in_sizes[0] / N_SAMPLES;   // 262144

    const int block = 256;                        // 4 waves -> 4 rays per block
    const int waves_per_block = block / 64;
    const int grid = (n_rays + waves_per_block - 1) / waves_per_block;

    VolumeRenderer_14336600834233_kernel<<<grid, block, 0, stream>>>(
        alpha, rgbs, out, n_rays);
}